// Round 13
// baseline (1184.801 us; speedup 1.0000x reference)
//
#include <hip/hip_runtime.h>
#include <hip/hip_fp8.h>

typedef unsigned short u16;
typedef float f32x4 __attribute__((ext_vector_type(4)));
typedef unsigned short u16x8 __attribute__((ext_vector_type(8)));
typedef unsigned short u16x4 __attribute__((ext_vector_type(4)));
typedef long i64;

typedef __attribute__((address_space(3))) unsigned char lds_u8_t;
typedef __attribute__((address_space(1))) const unsigned char glb_u8_t;

__device__ __forceinline__ u16 f2bf(float f) {
    union { float f; unsigned u; } v; v.f = f;
    unsigned r = v.u + 0x7FFFu + ((v.u >> 16) & 1u);   // RNE
    return (u16)(r >> 16);
}
__device__ __forceinline__ float bf2f(u16 h) {
    union { unsigned u; float f; } v; v.u = ((unsigned)h) << 16; return v.f;
}
__device__ __forceinline__ unsigned char f2e4m3(float f) {
    __hip_fp8_e4m3 h(f);               // OCP e4m3fn, RNE+sat
    return (unsigned char)h.__x;
}
// decode non-negative e4m3fn (P values are >= 0)
__device__ __forceinline__ float e4m32f(unsigned char b) {
    int e = (b >> 3) & 15, m = b & 7;
    union { unsigned u; float f; } p;
    p.u = (unsigned)(e ? e + 117 : 118) << 23;   // 2^(e-10) or 2^-9
    return (e ? (8 + m) : m) * p.f;
}

// ---------------- merged f32 -> fp8 cast: 9 segments, per-segment scale ----------------
struct CastQ { const float* s[9]; unsigned char* d[9]; long n4[9]; float mul[9]; };
__global__ __launch_bounds__(256) void castq_kernel(CastQ a) {
    int seg = blockIdx.z;
    const float* s = a.s[seg];
    unsigned char* d = a.d[seg];
    long n4 = a.n4[seg];
    float mul = a.mul[seg];
    long i = (long)blockIdx.x * 256 + threadIdx.x;
    long stride = (long)gridDim.x * 256;
    for (; i < n4; i += stride) {
        float4 f = reinterpret_cast<const float4*>(s)[i];
        uchar4 o;
        o.x = f2e4m3(f.x * mul); o.y = f2e4m3(f.y * mul);
        o.z = f2e4m3(f.z * mul); o.w = f2e4m3(f.w * mul);
        reinterpret_cast<uchar4*>(d)[i] = o;
    }
}

// ---------------- token + positional embedding (wave-per-row), bf16 + fp8 out + labels ----------------
__global__ __launch_bounds__(256) void embed_kernel(
    const int* __restrict__ labels, const float* __restrict__ tok_emb,
    const float* __restrict__ pos_emb, u16* __restrict__ xb,
    unsigned char* __restrict__ xq, float* __restrict__ lab_out)
{
    int wid = threadIdx.x >> 6, lane = threadIdx.x & 63;
    int r = blockIdx.x * 4 + wid;       // 0..8191 = b*512+t
    int b = r >> 9, t = r & 511;
    int tok = labels[b * 513 + t];      // labels[:, :-1]
    if (lane == 0) lab_out[r] = (float)labels[b * 513 + t + 1];
    const float* te = tok_emb + (long)tok * 768;
    const float* pe = pos_emb + (long)t * 768;
    u16* xo = xb + (long)r * 768;
    unsigned char* qo = xq + (long)r * 768;
    int base = lane * 12;
#pragma unroll
    for (int c = 0; c < 3; c++) {
        float4 a = *reinterpret_cast<const float4*>(te + base + c * 4);
        float4 p = *reinterpret_cast<const float4*>(pe + base + c * 4);
        float v0 = a.x + p.x, v1 = a.y + p.y, v2 = a.z + p.z, v3 = a.w + p.w;
        ushort4 o; o.x = f2bf(v0); o.y = f2bf(v1); o.z = f2bf(v2); o.w = f2bf(v3);
        *reinterpret_cast<ushort4*>(xo + base + c * 4) = o;
        uchar4 q; q.x = f2e4m3(v0); q.y = f2e4m3(v1); q.z = f2e4m3(v2); q.w = f2e4m3(v3);
        *reinterpret_cast<uchar4*>(qo + base + c * 4) = q;
    }
}

// ================= BMx128 FP8 MFMA GEMM, BK=64, 2-phase, swizzled LDS, BATCHED =================
// OUT: 0=f32, 1=bf16, 2=fp8. QKV: cols<1536 -> fp8 C (ld 1536); cols>=1536 -> fp8 V^T scatter.
// CMODE: 0=none, 2=causal K-limit (PV: Keff=min(K,m0+128), bit-exact).
template<int OUT, int RELU, int BM, int QKV, int CMODE>
__global__ __launch_bounds__(256, 4) void gemm8(
    const unsigned char* __restrict__ A, int lda, long sAb, long sAh,
    const unsigned char* __restrict__ W, int ldw, long sWb, long sWh,
    const float* __restrict__ bias, float outscale,
    void* __restrict__ C, int ldc, long sCb, long sCh,
    unsigned char* __restrict__ vt8,
    int M, int N, int K, int NH)
{
    constexpr int NREP = (BM == 128) ? 4 : 2;
    constexpr int AHALF = (BM == 128) ? 4096 : 2048;
    __shared__ __align__(16) unsigned char As0[BM * 64];
    __shared__ __align__(16) unsigned char As1[BM * 64];
    __shared__ __align__(16) unsigned char Bs0[128 * 64];
    __shared__ __align__(16) unsigned char Bs1[128 * 64];

    int z = blockIdx.z, zb = z / NH, zh = z % NH;
    const unsigned char* Ap = A + (long)zb * sAb + (long)zh * sAh;
    const unsigned char* Wp = W + (long)zb * sWb + (long)zh * sWh;
    long coff = (long)zb * sCb + (long)zh * sCh;

    int gx = (int)gridDim.x, gy = (int)gridDim.y;
    int nwg = gx * gy;
    int orig = (int)(blockIdx.y * gridDim.x + blockIdx.x);
    int q = nwg >> 3, r = nwg & 7;
    int xcd = orig & 7, loc = orig >> 3;
    int wg = (xcd < r ? xcd * (q + 1) : r * (q + 1) + (xcd - r) * q) + loc;
    int full = 8 * gy;
    int nsc = (gx + 7) >> 3;
    int sc = wg / full; if (sc > nsc - 1) sc = nsc - 1;
    int rem = wg - sc * full;
    int wdt = gx - sc * 8; if (wdt > 8) wdt = 8;
    int by = rem / wdt, bx = sc * 8 + rem % wdt;

    int m0 = by * BM, n0 = bx * 128;
    int Keff = K;
    if constexpr (CMODE == 2) { Keff = min(K, m0 + BM); }

    int tid = threadIdx.x, wid = tid >> 6, lane = tid & 63;
    int wr = (BM == 128) ? (wid >> 1) * 64 : 0;
    int wc = (BM == 128) ? (wid & 1) * 64 : wid * 32;
    int fr = lane & 15, gk = (lane >> 4) * 8;

    int li0 = wid * 64 + lane;
    int rsW = li0 >> 1, csW = li0 & 1;
    int kcW = ((csW ^ (rsW >> 2)) & 1) << 4;
    long woff = (long)min(n0 + rsW, N - 1) * ldw + kcW;
    long aoff;
    if constexpr (BM == 128) {
        aoff = (long)min(m0 + rsW, M - 1) * lda + kcW;
    } else {
        int halfA = li0 >> 7;
        int rsA = (li0 >> 1) & 63, csA = li0 & 1;
        int kcA = ((csA ^ (rsA >> 2)) & 1) << 4;
        aoff = (long)min(m0 + rsA, M - 1) * lda + halfA * 32 + kcA;
    }
    char* a0base = (char*)As0 + wid * 1024;
    char* a1base = (char*)As1 + wid * 1024;
    char* b0base = (char*)Bs0 + wid * 1024;
    char* b1base = (char*)Bs1 + wid * 1024;

    f32x4 acc[4][NREP] = {};

    auto stage = [&](char* ab, char* bb, int kt) {
        int k0 = kt * 64;
        if constexpr (BM == 128) {
            __builtin_amdgcn_global_load_lds((glb_u8_t*)(Ap + aoff + k0), (lds_u8_t*)ab, 16, 0, 0);
            __builtin_amdgcn_global_load_lds((glb_u8_t*)(Ap + aoff + k0 + 32), (lds_u8_t*)(ab + 4096), 16, 0, 0);
        } else {
            __builtin_amdgcn_global_load_lds((glb_u8_t*)(Ap + aoff + k0), (lds_u8_t*)ab, 16, 0, 0);
        }
        __builtin_amdgcn_global_load_lds((glb_u8_t*)(Wp + woff + k0), (lds_u8_t*)bb, 16, 0, 0);
        __builtin_amdgcn_global_load_lds((glb_u8_t*)(Wp + woff + k0 + 32), (lds_u8_t*)(bb + 4096), 16, 0, 0);
    };
    int cg = gk >> 4, go = gk & 15;
    auto compute = [&](const unsigned char* as, const unsigned char* bs) {
        i64 af[4][2], bw[NREP][2];
#pragma unroll
        for (int m = 0; m < 4; m++) {
            int rr2 = wr + m * 16 + fr;
            int off = rr2 * 32 + (((cg ^ (rr2 >> 2)) & 1) << 4) + go;
            af[m][0] = *reinterpret_cast<const i64*>(as + off);
            af[m][1] = *reinterpret_cast<const i64*>(as + AHALF + off);
        }
#pragma unroll
        for (int n = 0; n < NREP; n++) {
            int rr2 = wc + n * 16 + fr;
            int off = rr2 * 32 + (((cg ^ (rr2 >> 2)) & 1) << 4) + go;
            bw[n][0] = *reinterpret_cast<const i64*>(bs + off);
            bw[n][1] = *reinterpret_cast<const i64*>(bs + 4096 + off);
        }
#pragma unroll
        for (int ks = 0; ks < 2; ks++)
#pragma unroll
            for (int m = 0; m < 4; m++)
#pragma unroll
                for (int n = 0; n < NREP; n++)
                    acc[m][n] = __builtin_amdgcn_mfma_f32_16x16x32_fp8_fp8(
                        af[m][ks], bw[n][ks], acc[m][n], 0, 0, 0);
    };

    int nt = Keff >> 6;
    stage(a0base, b0base, 0);
    __syncthreads();
    for (int t = 0; t < nt; t += 2) {
        if (t + 1 < nt) stage(a1base, b1base, t + 1);
        compute(As0, Bs0);
        __syncthreads();
        if (t + 1 < nt) {
            if (t + 2 < nt) stage(a0base, b0base, t + 2);
            compute(As1, Bs1);
            __syncthreads();
        }
    }

    int crow = (lane >> 4) * 4;
#pragma unroll
    for (int m = 0; m < 4; m++) {
#pragma unroll
        for (int n = 0; n < NREP; n++) {
            int col = n0 + wc + n * 16 + fr;
            if (col >= N) continue;
            float bv = bias ? bias[col] : 0.f;
            int rbase = m0 + wr + m * 16 + crow;
            float vv[4];
#pragma unroll
            for (int rr = 0; rr < 4; rr++) {
                float v = acc[m][n][rr] * outscale + bv;
                if (RELU) v = fmaxf(v, 0.f);
                vv[rr] = v;
            }
            if constexpr (QKV) {
                if (col < 1536) {
#pragma unroll
                    for (int rr = 0; rr < 4; rr++)
                        ((unsigned char*)C)[coff + (long)(rbase + rr) * ldc + col] = f2e4m3(vv[rr]);
                } else {
                    int tt = col - 1536;
                    int h = tt / 192, d = tt - h * 192;
                    int b = rbase >> 9, k0 = rbase & 511;
                    uchar4 o;
                    o.x = f2e4m3(vv[0]); o.y = f2e4m3(vv[1]);
                    o.z = f2e4m3(vv[2]); o.w = f2e4m3(vv[3]);
                    *reinterpret_cast<uchar4*>(vt8 + ((long)((b << 2) + h) * 192 + d) * 512 + k0) = o;
                }
            } else {
#pragma unroll
                for (int rr = 0; rr < 4; rr++) {
                    int row = rbase + rr;
                    if (row >= M) continue;
                    long idx = coff + (long)row * ldc + col;
                    if (OUT == 0)      ((float*)C)[idx] = vv[rr];
                    else if (OUT == 1) ((u16*)C)[idx] = f2bf(vv[rr]);
                    else               ((unsigned char*)C)[idx] = f2e4m3(vv[rr]);
                }
            }
        }
    }
}

// ================= FUSED scores+softmax: S = Q K^T -> softmax -> fp8 probs x64 =================
// Block = one (b,h) [z] x one 128-q-row strip [y]. Grid (1,4,64), 256 thr, 4 waves 2x2.
// kv-tiles of 128 processed sequentially; P kept in LDS (fp8, per-tile-max normalized);
// final pass merges via log-sum-exp ledger and writes pr8 (layout identical to old softmax2).
// CAUSAL=1: tiles 0..y only, diagonal masked (PV CMODE=2 never reads beyond). CPL=8 SA / 4 CA.
template<int CAUSAL, int CPL>
__global__ __launch_bounds__(256) void fused_sm(
    const unsigned char* __restrict__ Q, int ldq, long sQb, long sQh,
    const unsigned char* __restrict__ Kin, int ldk, long sKb, long sKh,
    int krows,
    unsigned char* __restrict__ P, int ldp, long sPz,
    float scale)
{
    __shared__ __align__(16) unsigned char Qs[6 * 4096];   // 128 q-rows x 192 k (6 halves)
    __shared__ __align__(16) unsigned char Ks[6 * 4096];   // 128 kv-rows x 192 k
    __shared__ __align__(16) unsigned char Sl[4 * 16384];  // up to 4 tiles of P (fp8)
    __shared__ float mt[4][128];                           // per-tile row max (raw S)
    __shared__ float rsL[4][128];                          // per-tile row sum of P
    __shared__ float tmpm[2][128], tmps[2][128];

    int tid = threadIdx.x, wid = tid >> 6, lane = tid & 63;
    int wr = (wid >> 1) * 64, wc = (wid & 1) * 64;
    int fl = lane & 15, g = lane >> 4;
    int cg = g >> 1, go = (g & 1) * 8;
    int y = blockIdx.y, z = blockIdx.z, zb = z >> 2, zh = z & 3;
    const unsigned char* Qp = Q + (long)zb * sQb + (long)zh * sQh;
    const unsigned char* Kp2 = Kin + (long)zb * sKb + (long)zh * sKh;
    int KT = CAUSAL ? (y + 1) : (CPL / 2);

    // staging geometry (validated swizzle: 16B chunk ^= (row>>2)&1)
    int srow = tid >> 1, scs = tid & 1;
    int skc = ((scs ^ (srow >> 2)) & 1) << 4;

    {   // stage Q strip + K tile 0
        const unsigned char* qb = Qp + (long)(y * 128 + srow) * ldq + skc;
#pragma unroll
        for (int hh = 0; hh < 6; hh++)
            __builtin_amdgcn_global_load_lds((glb_u8_t*)(qb + hh * 32),
                (lds_u8_t*)(Qs + hh * 4096 + wid * 1024), 16, 0, 0);
        const unsigned char* kb = Kp2 + (long)min(srow, krows - 1) * ldk + skc;
#pragma unroll
        for (int hh = 0; hh < 6; hh++)
            __builtin_amdgcn_global_load_lds((glb_u8_t*)(kb + hh * 32),
                (lds_u8_t*)(Ks + hh * 4096 + wid * 1024), 16, 0, 0);
    }
    __syncthreads();

    for (int kt = 0; kt < KT; ++kt) {
        // ---- S tile MFMA (K=192 = 3 BK-64 steps) ----
        f32x4 acc[4][4] = {};
#pragma unroll
        for (int t = 0; t < 3; ++t) {
            i64 af[4][2], bw[4][2];
#pragma unroll
            for (int m = 0; m < 4; m++) {
                int rr2 = wr + m * 16 + fl;
                int off = rr2 * 32 + (((cg ^ (rr2 >> 2)) & 1) << 4) + go;
                af[m][0] = *reinterpret_cast<const i64*>(Qs + (2 * t) * 4096 + off);
                af[m][1] = *reinterpret_cast<const i64*>(Qs + (2 * t + 1) * 4096 + off);
            }
#pragma unroll
            for (int n = 0; n < 4; n++) {
                int rr2 = wc + n * 16 + fl;
                int off = rr2 * 32 + (((cg ^ (rr2 >> 2)) & 1) << 4) + go;
                bw[n][0] = *reinterpret_cast<const i64*>(Ks + (2 * t) * 4096 + off);
                bw[n][1] = *reinterpret_cast<const i64*>(Ks + (2 * t + 1) * 4096 + off);
            }
#pragma unroll
            for (int ks = 0; ks < 2; ks++)
#pragma unroll
                for (int m = 0; m < 4; m++)
#pragma unroll
                    for (int n = 0; n < 4; n++)
                        acc[m][n] = __builtin_amdgcn_mfma_f32_16x16x32_fp8_fp8(
                            af[m][ks], bw[n][ks], acc[m][n], 0, 0, 0);
        }
        // ---- pass 1: per-wave masked row max ----
        float rmx[4][4];
#pragma unroll
        for (int m = 0; m < 4; m++)
#pragma unroll
        for (int rr = 0; rr < 4; rr++) {
            int rl = wr + m * 16 + g * 4 + rr;
            int rowg = y * 128 + rl;
            float mx = -3e38f;
#pragma unroll
            for (int n = 0; n < 4; n++) {
                int col = kt * 128 + wc + n * 16 + fl;
                bool ok = CAUSAL ? (col <= rowg) : (col < krows);
                if (ok) mx = fmaxf(mx, acc[m][n][rr]);
            }
            mx = fmaxf(mx, __shfl_xor(mx, 1, 64));
            mx = fmaxf(mx, __shfl_xor(mx, 2, 64));
            mx = fmaxf(mx, __shfl_xor(mx, 4, 64));
            mx = fmaxf(mx, __shfl_xor(mx, 8, 64));
            rmx[m][rr] = mx;
            if (fl == 0) tmpm[wid & 1][rl] = mx;
        }
        __syncthreads();                       // A: tmpm visible; all Ks reads done
        if (kt + 1 < KT) {                     // prefetch next K tile (drained at barrier B)
            const unsigned char* kb = Kp2 + (long)min((kt + 1) * 128 + srow, krows - 1) * ldk + skc;
#pragma unroll
            for (int hh = 0; hh < 6; hh++)
                __builtin_amdgcn_global_load_lds((glb_u8_t*)(kb + hh * 32),
                    (lds_u8_t*)(Ks + hh * 4096 + wid * 1024), 16, 0, 0);
        }
        // ---- combined max + pass 2: P=exp, store fp8, row sums ----
#pragma unroll
        for (int m = 0; m < 4; m++)
#pragma unroll
        for (int rr = 0; rr < 4; rr++) {
            int rl = wr + m * 16 + g * 4 + rr;
            float cm = fmaxf(tmpm[0][rl], tmpm[1][rl]);
            rmx[m][rr] = cm;
            if (fl == 0 && (wid & 1) == 0) mt[kt][rl] = cm;
        }
#pragma unroll
        for (int m = 0; m < 4; m++)
#pragma unroll
        for (int rr = 0; rr < 4; rr++) {
            int rl = wr + m * 16 + g * 4 + rr;
            int rowg = y * 128 + rl;
            int swz = ((rl >> 2) & 3) << 4;
            float sum = 0.f;
#pragma unroll
            for (int n = 0; n < 4; n++) {
                int ct = wc + n * 16 + fl;
                int col = kt * 128 + ct;
                bool ok = CAUSAL ? (col <= rowg) : (col < krows);
                float pv = ok ? __expf((acc[m][n][rr] - rmx[m][rr]) * scale) : 0.f;
                sum += pv;
                Sl[kt * 16384 + rl * 128 + (ct ^ swz)] = f2e4m3(pv);
            }
            sum += __shfl_xor(sum, 1, 64);
            sum += __shfl_xor(sum, 2, 64);
            sum += __shfl_xor(sum, 4, 64);
            sum += __shfl_xor(sum, 8, 64);
            if (fl == 0) tmps[wid & 1][rl] = sum;
        }
        __syncthreads();                       // B: tmps/P visible; next K tile ready
#pragma unroll
        for (int m = 0; m < 4; m++)
#pragma unroll
        for (int rr = 0; rr < 4; rr++) {
            int rl = wr + m * 16 + g * 4 + rr;
            if (fl == 0 && (wid & 1) == 0) rsL[kt][rl] = tmps[0][rl] + tmps[1][rl];
        }
    }
    __syncthreads();                           // C: ledger complete

    // ---- final: merge tiles (log-sum-exp), emit probs x64 ----
    for (int r8 = 0; r8 < 32; ++r8) {
        int rl = wid * 32 + r8;
        float mf = -3e38f;
        for (int kt = 0; kt < KT; ++kt) mf = fmaxf(mf, mt[kt][rl]);
        float l = 0.f;
        for (int kt = 0; kt < KT; ++kt) l += rsL[kt][rl] * __expf((mt[kt][rl] - mf) * scale);
        int cw0 = lane * CPL;
        int tile = cw0 >> 7;
        if (tile < KT) {
            float ft = __expf((mt[tile][rl] - mf) * scale) * 64.f / l;
            int swz = ((rl >> 2) & 3) << 4;
            const unsigned char* src = Sl + tile * 16384 + rl * 128 + ((cw0 & 127) ^ swz);
            unsigned char* dst = P + (long)z * sPz + (long)(y * 128 + rl) * ldp + cw0;
            if constexpr (CPL == 8) {
                i64 v8 = *reinterpret_cast<const i64*>(src);
                const unsigned char* bp = reinterpret_cast<const unsigned char*>(&v8);
                union { unsigned char b[8]; i64 v; } o;
#pragma unroll
                for (int j = 0; j < 8; j++) o.b[j] = f2e4m3(e4m32f(bp[j]) * ft);
                *reinterpret_cast<i64*>(dst) = o.v;
            } else {
                unsigned v4 = *reinterpret_cast<const unsigned*>(src);
                const unsigned char* bp = reinterpret_cast<const unsigned char*>(&v4);
                union { unsigned char b[4]; unsigned v; } o;
#pragma unroll
                for (int j = 0; j < 4; j++) o.b[j] = f2e4m3(e4m32f(bp[j]) * ft);
                *reinterpret_cast<unsigned*>(dst) = o.v;
            }
        }
    }
}

// ---------------- fp8 V transpose with zero-pad (CA only) ----------------
__global__ __launch_bounds__(256) void transpose_pad8(
    const unsigned char* __restrict__ V, long sVb, long sVh, int ldv, int NH,
    unsigned char* __restrict__ VT, long sVT, int rowsIn, int Kp)
{
    __shared__ unsigned char tile[32][33];
    int z = blockIdx.z, zb = z / NH, zh = z % NH;
    const unsigned char* Vp = V + (long)zb * sVb + (long)zh * sVh;
    int k0 = blockIdx.x * 32, d0 = blockIdx.y * 32;
#pragma unroll
    for (int i = 0; i < 4; i++) {
        int k = k0 + threadIdx.y + i * 8;
        int d = d0 + threadIdx.x;
        tile[threadIdx.y + i * 8][threadIdx.x] = (k < rowsIn) ? Vp[(long)k * ldv + d] : (unsigned char)0;
    }
    __syncthreads();
    unsigned char* Op = VT + (long)z * sVT;
#pragma unroll
    for (int i = 0; i < 4; i++) {
        int d = d0 + threadIdx.y + i * 8;
        int k = k0 + threadIdx.x;
        Op[(long)d * Kp + k] = tile[threadIdx.x][threadIdx.y + i * 8];
    }
}

// ---------------- fused residual add + LayerNorm (bf16 in/out + fp8 out) ----------------
__global__ __launch_bounds__(256) void ln_kernel(
    const u16* __restrict__ xin, const u16* __restrict__ subb,
    const float* __restrict__ g, const float* __restrict__ bta,
    u16* __restrict__ xout, unsigned char* __restrict__ q8)
{
    int wid = threadIdx.x >> 6, lane = threadIdx.x & 63;
    long r = (long)blockIdx.x * 4 + wid;
    const u16* a = xin + r * 768;
    const u16* s = subb + r * 768;
    int base = lane * 12;
    float v[12];
    float sum = 0.f;
#pragma unroll
    for (int c = 0; c < 3; c++) {
        ushort4 av = *reinterpret_cast<const ushort4*>(a + base + c * 4);
        ushort4 sv = *reinterpret_cast<const ushort4*>(s + base + c * 4);
        v[c*4+0] = bf2f(av.x) + bf2f(sv.x);
        v[c*4+1] = bf2f(av.y) + bf2f(sv.y);
        v[c*4+2] = bf2f(av.z) + bf2f(sv.z);
        v[c*4+3] = bf2f(av.w) + bf2f(sv.w);
        sum += v[c*4+0] + v[c*4+1] + v[c*4+2] + v[c*4+3];
    }
#pragma unroll
    for (int o = 32; o; o >>= 1) sum += __shfl_xor(sum, o, 64);
    float mean = sum * (1.f / 768.f);
    float vs = 0.f;
#pragma unroll
    for (int j = 0; j < 12; j++) { float t = v[j] - mean; vs += t * t; }
#pragma unroll
    for (int o = 32; o; o >>= 1) vs += __shfl_xor(vs, o, 64);
    float rstd = rsqrtf(vs * (1.f / 768.f) + 1e-5f);
    u16* xo = xout + r * 768;
    unsigned char* qo = q8 + r * 768;
#pragma unroll
    for (int c = 0; c < 3; c++) {
        float4 gv = *reinterpret_cast<const float4*>(g + base + c * 4);
        float4 bv = *reinterpret_cast<const float4*>(bta + base + c * 4);
        float y0 = (v[c*4+0] - mean) * rstd * gv.x + bv.x;
        float y1 = (v[c*4+1] - mean) * rstd * gv.y + bv.y;
        float y2 = (v[c*4+2] - mean) * rstd * gv.z + bv.z;
        float y3 = (v[c*4+3] - mean) * rstd * gv.w + bv.w;
        ushort4 o; o.x = f2bf(y0); o.y = f2bf(y1); o.z = f2bf(y2); o.w = f2bf(y3);
        *reinterpret_cast<ushort4*>(xo + base + c * 4) = o;
        uchar4 qb; qb.x = f2e4m3(y0); qb.y = f2e4m3(y1); qb.z = f2e4m3(y2); qb.w = f2e4m3(y3);
        *reinterpret_cast<uchar4*>(qo + base + c * 4) = qb;
    }
}

// ---------------- host helpers ----------------
template<int OUT, int RELU, int BM>
static void g8(hipStream_t st, const unsigned char* A, int lda, const unsigned char* W, int ldw,
               const float* bias, void* C, int ldc, int M, int N, int K) {
    dim3 g((N + 127) / 128, (M + BM - 1) / BM, 1), b(256, 1, 1);
    gemm8<OUT,RELU,BM,0,0><<<g,b,0,st>>>(A,lda,0,0,W,ldw,0,0,bias,1.f/256.f,C,ldc,0,0,nullptr,M,N,K,1);
}
template<int OUT, int CMODE>
static void g8bat(hipStream_t st,
    const unsigned char* A, int lda, long sAb, long sAh,
    const unsigned char* W, int ldw, long sWb, long sWh,
    float outscale, void* C, int ldc, long sCb, long sCh,
    int M, int N, int K, int Z, int NH) {
    dim3 g((N + 127) / 128, (M + 127) / 128, Z), b(256, 1, 1);
    gemm8<OUT,0,128,0,CMODE><<<g,b,0,st>>>(A,lda,sAb,sAh,W,ldw,sWb,sWh,nullptr,outscale,
                                           C,ldc,sCb,sCh,nullptr,M,N,K,NH);
}
static void g8qkv(hipStream_t st, const unsigned char* A, const unsigned char* W,
                  const float* bias, unsigned char* q8k8, unsigned char* vt8) {
    dim3 g(18, 64, 1), b(256, 1, 1);
    gemm8<2,0,128,1,0><<<g,b,0,st>>>(A,768,0,0,W,768,0,0,bias,1.f/256.f,
                                     q8k8,1536,0,0,vt8,8192,2304,768,1);
}

extern "C" void kernel_launch(void* const* d_in, const int* in_sizes, int n_in,
                              void* d_out, int out_size, void* d_ws, size_t ws_size,
                              hipStream_t stream)
{
    const int*   labels = (const int*)  d_in[0];
    const float* vision = (const float*)d_in[1];
    const float* vpw    = (const float*)d_in[2];
    const float* vpb    = (const float*)d_in[3];
    const float* temb   = (const float*)d_in[4];
    const float* pemb   = (const float*)d_in[5];
    const float* saw    = (const float*)d_in[6];
    const float* sab    = (const float*)d_in[7];
    const float* saow   = (const float*)d_in[8];
    const float* saob   = (const float*)d_in[9];
    const float* caw    = (const float*)d_in[10];
    const float* cab    = (const float*)d_in[11];
    const float* caow   = (const float*)d_in[12];
    const float* caob   = (const float*)d_in[13];
    const float* ln1g   = (const float*)d_in[14];
    const float* ln1b   = (const float*)d_in[15];
    const float* ln2g   = (const float*)d_in[16];
    const float* ln2b   = (const float*)d_in[17];
    const float* ln3g   = (const float*)d_in[18];
    const float* ln3b   = (const float*)d_in[19];
    const float* f1w    = (const float*)d_in[20];
    const float* f1b    = (const float*)d_in[21];
    const float* f2w    = (const float*)d_in[22];
    const float* f2b    = (const float*)d_in[23];
    const float* ow     = (const float*)d_in[24];
    const float* ob     = (const float*)d_in[25];
    (void)in_sizes; (void)n_in; (void)out_size;

    // ---- workspace layout ----
    char* p = (char*)d_ws;
    auto alloc = [&](long elems, int esz) -> char* {
        char* r = p; p += ((long)elems * esz + 255) & ~255L; return r;
    };
    unsigned char* w8_sa  = (unsigned char*)alloc(3L*2304*768, 1);  // fp8 weights x256
    unsigned char* w8_ca  = (unsigned char*)alloc(3L*2304*768, 1);
    unsigned char* w8_sao = (unsigned char*)alloc(3L*768*768, 1);
    unsigned char* w8_cao = (unsigned char*)alloc(3L*768*768, 1);
    unsigned char* w8_f1  = (unsigned char*)alloc(3L*1024*768, 1);
    unsigned char* w8_f2  = (unsigned char*)alloc(3L*768*1024, 1);
    unsigned char* w8_ow  = (unsigned char*)alloc(10000L*768, 1);
    unsigned char* w8_vp  = (unsigned char*)alloc(768L*768, 1);
    unsigned char* vis8   = (unsigned char*)alloc(3152L*768, 1);    // fp8 activations (x1)
    unsigned char* mem8   = (unsigned char*)alloc(3152L*768, 1);
    unsigned char* xq     = (unsigned char*)alloc(8192L*768, 1);
    unsigned char* h8     = (unsigned char*)alloc(8192L*1024, 1);
    unsigned char* attn8  = (unsigned char*)alloc(8192L*768, 1);
    unsigned char* q8k8   = (unsigned char*)alloc(8192L*1536, 1);   // SA Q|K fp8
    unsigned char* q8ca   = (unsigned char*)alloc(8192L*768, 1);    // CA Q fp8
    unsigned char* kv8    = (unsigned char*)alloc(3152L*1536, 1);   // CA K|V fp8
    unsigned char* vt8    = (unsigned char*)alloc(64L*192*512, 1);  // V^T fp8 (SA Kp512 / CA Kp256)
    unsigned char* pr8    = (unsigned char*)alloc(64L*512*512, 1);  // probs fp8 x64
    u16* xb   = (u16*)alloc(8192L*768, 2);
    u16* subb = (u16*)alloc(8192L*768, 2);
    if ((size_t)(p - (char*)d_ws) > ws_size) return;

    // ---- all casts -> fp8 in one launch (weights x256, vision x1) ----
    CastQ cq;
    cq.s[0] = saw;    cq.d[0] = w8_sa;  cq.n4[0] = 3L*2304*768/4;  cq.mul[0] = 256.f;
    cq.s[1] = caw;    cq.d[1] = w8_ca;  cq.n4[1] = 3L*2304*768/4;  cq.mul[1] = 256.f;
    cq.s[2] = saow;   cq.d[2] = w8_sao; cq.n4[2] = 3L*768*768/4;   cq.mul[2] = 256.f;
    cq.s[3] = caow;   cq.d[3] = w8_cao; cq.n4[3] = 3L*768*768/4;   cq.mul[3] = 256.f;
    cq.s[4] = f1w;    cq.d[4] = w8_f1;  cq.n4[4] = 3L*1024*768/4;  cq.mul[4] = 256.f;
    cq.s[5] = f2w;    cq.d[5] = w8_f2;  cq.n4[5] = 3L*768*1024/4;  cq.mul[5] = 256.f;
    cq.s[6] = ow;     cq.d[6] = w8_ow;  cq.n4[6] = 10000L*768/4;   cq.mul[6] = 256.f;
    cq.s[7] = vpw;    cq.d[7] = w8_vp;  cq.n4[7] = 768L*768/4;     cq.mul[7] = 256.f;
    cq.s[8] = vision; cq.d[8] = vis8;   cq.n4[8] = 3152L*768/4;    cq.mul[8] = 1.f;
    castq_kernel<<<dim3(512, 1, 9), dim3(256), 0, stream>>>(cq);

    embed_kernel<<<dim3(2048), dim3(256), 0, stream>>>(labels, temb, pemb, xb, xq,
                                                       (float*)d_out + 81920000L);

    // mem = vision @ vis_proj_w^T + b  -> fp8
    g8<2,0,64>(stream, vis8, 768, w8_vp, 768, vpb, mem8, 768, 3152, 768, 768);

    const float scale = 0.07216878364870323f;  // 1/sqrt(192)
    const float PSCALE_INV = 1.f / 64.f;

    for (int l = 0; l < 3; l++) {
        // ======== self-attention (fp8, fused scores+softmax) ========
        g8qkv(stream, xq, w8_sa + (long)l*2304*768, sab + l*2304, q8k8, vt8);
        fused_sm<1,8><<<dim3(1,4,64), dim3(256), 0, stream>>>(
            q8k8, 1536, 512L*1536, 192, q8k8 + 768, 1536, 512L*1536, 192,
            512, pr8, 512, 512L*512, scale);
        g8bat<2,2>(stream, pr8, 512, 4L*512*512, 512L*512, vt8, 512, 4L*192*512, 192L*512,
                   PSCALE_INV, attn8, 768, 512L*768, 192, 512, 192, 512, 64, 4);
        g8<1,0,64>(stream, attn8, 768, w8_sao + (long)l*768*768, 768,
                   saob + l*768, subb, 768, 8192, 768, 768);
        ln_kernel<<<dim3(2048), dim3(256), 0, stream>>>(xb, subb, ln1g + l*768, ln1b + l*768,
                                                        xb, xq);

        // ======== cross-attention (fp8, fused scores+softmax) ========
        g8<2,0,64>(stream, xq, 768, w8_ca + (long)l*2304*768, 768,
                   cab + l*2304, q8ca, 768, 8192, 768, 768);
        g8<2,0,64>(stream, mem8, 768, w8_ca + (long)l*2304*768 + 768L*768, 768,
                   cab + l*2304 + 768, kv8, 1536, 3152, 1536, 768);
        transpose_pad8<<<dim3(8,6,64), dim3(32,8), 0, stream>>>(
            kv8 + 768, 197L*1536, 192L, 1536, 4, vt8, 192L*256, 197, 256);
        fused_sm<0,4><<<dim3(1,4,64), dim3(256), 0, stream>>>(
            q8ca, 768, 512L*768, 192, kv8, 1536, 197L*1536, 192,
            197, pr8, 256, 512L*256, scale);
        g8bat<2,0>(stream, pr8, 256, 4L*512*256, 512L*256, vt8, 256, 4L*192*256, 192L*256,
                   PSCALE_INV, attn8, 768, 512L*768, 192, 512, 192, 256, 64, 4);
        g8<1,0,64>(stream, attn8, 768, w8_cao + (long)l*768*768, 768,
                   caob + l*768, subb, 768, 8192, 768, 768);
        ln_kernel<<<dim3(2048), dim3(256), 0, stream>>>(xb, subb, ln2g + l*768, ln2b + l*768,
                                                        xb, xq);

        // ======== feed-forward (fp8) ========
        g8<2,1,128>(stream, xq, 768, w8_f1 + (long)l*1024*768, 768, f1b + l*1024,
                    h8, 1024, 8192, 1024, 768);
        g8<1,0,64>(stream, h8, 1024, w8_f2 + (long)l*768*1024, 1024, f2b + l*768,
                   subb, 768, 8192, 768, 1024);
        ln_kernel<<<dim3(2048), dim3(256), 0, stream>>>(xb, subb, ln3g + l*768, ln3b + l*768,
                                                        xb, xq);
    }

    // vocab head (fp8, BM=128) -> d_out f32 logits
    g8<0,0,128>(stream, xq, 768, w8_ow, 768, ob, (float*)d_out, 10000, 8192, 10000, 768);
}

// Round 14
// 1067.639 us; speedup vs baseline: 1.1097x; 1.1097x over previous
//
#include <hip/hip_runtime.h>
#include <hip/hip_fp8.h>

typedef unsigned short u16;
typedef float f32x4 __attribute__((ext_vector_type(4)));
typedef unsigned short u16x8 __attribute__((ext_vector_type(8)));
typedef unsigned short u16x4 __attribute__((ext_vector_type(4)));
typedef long i64;

typedef __attribute__((address_space(3))) unsigned char lds_u8_t;
typedef __attribute__((address_space(1))) const unsigned char glb_u8_t;

__device__ __forceinline__ u16 f2bf(float f) {
    union { float f; unsigned u; } v; v.f = f;
    unsigned r = v.u + 0x7FFFu + ((v.u >> 16) & 1u);   // RNE
    return (u16)(r >> 16);
}
__device__ __forceinline__ float bf2f(u16 h) {
    union { unsigned u; float f; } v; v.u = ((unsigned)h) << 16; return v.f;
}
__device__ __forceinline__ unsigned char f2e4m3(float f) {
    __hip_fp8_e4m3 h(f);               // OCP e4m3fn, RNE+sat
    return (unsigned char)h.__x;
}

// ---------------- merged f32 -> fp8 cast: 9 segments, per-segment scale ----------------
struct CastQ { const float* s[9]; unsigned char* d[9]; long n4[9]; float mul[9]; };
__global__ __launch_bounds__(256) void castq_kernel(CastQ a) {
    int seg = blockIdx.z;
    const float* s = a.s[seg];
    unsigned char* d = a.d[seg];
    long n4 = a.n4[seg];
    float mul = a.mul[seg];
    long i = (long)blockIdx.x * 256 + threadIdx.x;
    long stride = (long)gridDim.x * 256;
    for (; i < n4; i += stride) {
        float4 f = reinterpret_cast<const float4*>(s)[i];
        uchar4 o;
        o.x = f2e4m3(f.x * mul); o.y = f2e4m3(f.y * mul);
        o.z = f2e4m3(f.z * mul); o.w = f2e4m3(f.w * mul);
        reinterpret_cast<uchar4*>(d)[i] = o;
    }
}

// ---------------- token + positional embedding (wave-per-row), bf16 + fp8 out + labels ----------------
__global__ __launch_bounds__(256) void embed_kernel(
    const int* __restrict__ labels, const float* __restrict__ tok_emb,
    const float* __restrict__ pos_emb, u16* __restrict__ xb,
    unsigned char* __restrict__ xq, float* __restrict__ lab_out)
{
    int wid = threadIdx.x >> 6, lane = threadIdx.x & 63;
    int r = blockIdx.x * 4 + wid;       // 0..8191 = b*512+t
    int b = r >> 9, t = r & 511;
    int tok = labels[b * 513 + t];      // labels[:, :-1]
    if (lane == 0) lab_out[r] = (float)labels[b * 513 + t + 1];
    const float* te = tok_emb + (long)tok * 768;
    const float* pe = pos_emb + (long)t * 768;
    u16* xo = xb + (long)r * 768;
    unsigned char* qo = xq + (long)r * 768;
    int base = lane * 12;
#pragma unroll
    for (int c = 0; c < 3; c++) {
        float4 a = *reinterpret_cast<const float4*>(te + base + c * 4);
        float4 p = *reinterpret_cast<const float4*>(pe + base + c * 4);
        float v0 = a.x + p.x, v1 = a.y + p.y, v2 = a.z + p.z, v3 = a.w + p.w;
        ushort4 o; o.x = f2bf(v0); o.y = f2bf(v1); o.z = f2bf(v2); o.w = f2bf(v3);
        *reinterpret_cast<ushort4*>(xo + base + c * 4) = o;
        uchar4 q; q.x = f2e4m3(v0); q.y = f2e4m3(v1); q.z = f2e4m3(v2); q.w = f2e4m3(v3);
        *reinterpret_cast<uchar4*>(qo + base + c * 4) = q;
    }
}

// ================= BMx128 FP8 MFMA GEMM, BK=64, 2-phase, swizzled LDS, BATCHED =================
// LDS per matrix: halves (k 0..31 / 32..63), 32-B rows, 16-B chunk ^= (row>>2)&1 on BOTH sides.
// OUT: 0=f32, 1=bf16, 2=fp8. QKV: cols<1536 -> fp8 C (ld 1536); cols>=1536 -> fp8 V^T scatter.
// CMODE: 0=none, 1=causal block-skip (scores: n0>m0+127 never read by softmax),
//        2=causal K-limit (PV: P[q][k]=0 exactly for k>q -> Keff=min(K,m0+128), bit-exact).
// Guarded 2-phase loop handles odd nt (K=192). Batch z = zb*NH + zh.
template<int OUT, int RELU, int BM, int QKV, int CMODE>
__global__ __launch_bounds__(256, 4) void gemm8(
    const unsigned char* __restrict__ A, int lda, long sAb, long sAh,
    const unsigned char* __restrict__ W, int ldw, long sWb, long sWh,
    const float* __restrict__ bias, float outscale,
    void* __restrict__ C, int ldc, long sCb, long sCh,
    unsigned char* __restrict__ vt8,
    int M, int N, int K, int NH)
{
    constexpr int NREP = (BM == 128) ? 4 : 2;
    constexpr int AHALF = (BM == 128) ? 4096 : 2048;
    __shared__ __align__(16) unsigned char As0[BM * 64];
    __shared__ __align__(16) unsigned char As1[BM * 64];
    __shared__ __align__(16) unsigned char Bs0[128 * 64];
    __shared__ __align__(16) unsigned char Bs1[128 * 64];

    int z = blockIdx.z, zb = z / NH, zh = z % NH;
    const unsigned char* Ap = A + (long)zb * sAb + (long)zh * sAh;
    const unsigned char* Wp = W + (long)zb * sWb + (long)zh * sWh;
    long coff = (long)zb * sCb + (long)zh * sCh;

    int gx = (int)gridDim.x, gy = (int)gridDim.y;
    int nwg = gx * gy;
    int orig = (int)(blockIdx.y * gridDim.x + blockIdx.x);
    int q = nwg >> 3, r = nwg & 7;
    int xcd = orig & 7, loc = orig >> 3;
    int wg = (xcd < r ? xcd * (q + 1) : r * (q + 1) + (xcd - r) * q) + loc;
    int full = 8 * gy;
    int nsc = (gx + 7) >> 3;
    int sc = wg / full; if (sc > nsc - 1) sc = nsc - 1;
    int rem = wg - sc * full;
    int wdt = gx - sc * 8; if (wdt > 8) wdt = 8;
    int by = rem / wdt, bx = sc * 8 + rem % wdt;

    int m0 = by * BM, n0 = bx * 128;

    // causal block-skip: these score columns are never read by the causal softmax (exact)
    if constexpr (CMODE == 1) { if (n0 > m0 + BM - 1) return; }
    int Keff = K;
    if constexpr (CMODE == 2) { Keff = min(K, m0 + BM); }   // P is exactly 0 beyond q+1

    int tid = threadIdx.x, wid = tid >> 6, lane = tid & 63;
    int wr = (BM == 128) ? (wid >> 1) * 64 : 0;
    int wc = (BM == 128) ? (wid & 1) * 64 : wid * 32;
    int fr = lane & 15, gk = (lane >> 4) * 8;

    // ---- staging geometry (validated swizzle: chunk ^= (row>>2)&1) ----
    int li0 = wid * 64 + lane;
    int rsW = li0 >> 1, csW = li0 & 1;
    int kcW = ((csW ^ (rsW >> 2)) & 1) << 4;
    long woff = (long)min(n0 + rsW, N - 1) * ldw + kcW;
    long aoff;
    if constexpr (BM == 128) {
        aoff = (long)min(m0 + rsW, M - 1) * lda + kcW;
    } else {
        int halfA = li0 >> 7;
        int rsA = (li0 >> 1) & 63, csA = li0 & 1;
        int kcA = ((csA ^ (rsA >> 2)) & 1) << 4;
        aoff = (long)min(m0 + rsA, M - 1) * lda + halfA * 32 + kcA;
    }
    char* a0base = (char*)As0 + wid * 1024;
    char* a1base = (char*)As1 + wid * 1024;
    char* b0base = (char*)Bs0 + wid * 1024;
    char* b1base = (char*)Bs1 + wid * 1024;

    f32x4 acc[4][NREP] = {};

    auto stage = [&](char* ab, char* bb, int kt) {
        int k0 = kt * 64;
        if constexpr (BM == 128) {
            __builtin_amdgcn_global_load_lds((glb_u8_t*)(Ap + aoff + k0), (lds_u8_t*)ab, 16, 0, 0);
            __builtin_amdgcn_global_load_lds((glb_u8_t*)(Ap + aoff + k0 + 32), (lds_u8_t*)(ab + 4096), 16, 0, 0);
        } else {
            __builtin_amdgcn_global_load_lds((glb_u8_t*)(Ap + aoff + k0), (lds_u8_t*)ab, 16, 0, 0);
        }
        __builtin_amdgcn_global_load_lds((glb_u8_t*)(Wp + woff + k0), (lds_u8_t*)bb, 16, 0, 0);
        __builtin_amdgcn_global_load_lds((glb_u8_t*)(Wp + woff + k0 + 32), (lds_u8_t*)(bb + 4096), 16, 0, 0);
    };
    int cg = gk >> 4, go = gk & 15;
    auto compute = [&](const unsigned char* as, const unsigned char* bs) {
        i64 af[4][2], bw[NREP][2];
#pragma unroll
        for (int m = 0; m < 4; m++) {
            int rr2 = wr + m * 16 + fr;
            int off = rr2 * 32 + (((cg ^ (rr2 >> 2)) & 1) << 4) + go;
            af[m][0] = *reinterpret_cast<const i64*>(as + off);
            af[m][1] = *reinterpret_cast<const i64*>(as + AHALF + off);
        }
#pragma unroll
        for (int n = 0; n < NREP; n++) {
            int rr2 = wc + n * 16 + fr;
            int off = rr2 * 32 + (((cg ^ (rr2 >> 2)) & 1) << 4) + go;
            bw[n][0] = *reinterpret_cast<const i64*>(bs + off);
            bw[n][1] = *reinterpret_cast<const i64*>(bs + 4096 + off);
        }
#pragma unroll
        for (int ks = 0; ks < 2; ks++)
#pragma unroll
            for (int m = 0; m < 4; m++)
#pragma unroll
                for (int n = 0; n < NREP; n++)
                    acc[m][n] = __builtin_amdgcn_mfma_f32_16x16x32_fp8_fp8(
                        af[m][ks], bw[n][ks], acc[m][n], 0, 0, 0);
    };

    // guarded 2-phase loop: correct for any nt >= 1 (nt=3 for K=192)
    int nt = Keff >> 6;
    stage(a0base, b0base, 0);
    __syncthreads();
    for (int t = 0; t < nt; t += 2) {
        if (t + 1 < nt) stage(a1base, b1base, t + 1);
        compute(As0, Bs0);
        __syncthreads();
        if (t + 1 < nt) {
            if (t + 2 < nt) stage(a0base, b0base, t + 2);
            compute(As1, Bs1);
            __syncthreads();
        }
    }

    int crow = (lane >> 4) * 4;
#pragma unroll
    for (int m = 0; m < 4; m++) {
#pragma unroll
        for (int n = 0; n < NREP; n++) {
            int col = n0 + wc + n * 16 + fr;
            if (col >= N) continue;
            float bv = bias ? bias[col] : 0.f;
            int rbase = m0 + wr + m * 16 + crow;
            float vv[4];
#pragma unroll
            for (int rr = 0; rr < 4; rr++) {
                float v = acc[m][n][rr] * outscale + bv;
                if (RELU) v = fmaxf(v, 0.f);
                vv[rr] = v;
            }
            if constexpr (QKV) {
                // M=8192, N=2304 exact: no edge checks. cols<1536 -> q8k8; else V^T fp8 scatter.
                if (col < 1536) {
#pragma unroll
                    for (int rr = 0; rr < 4; rr++)
                        ((unsigned char*)C)[coff + (long)(rbase + rr) * ldc + col] = f2e4m3(vv[rr]);
                } else {
                    int tt = col - 1536;
                    int h = tt / 192, d = tt - h * 192;
                    int b = rbase >> 9, k0 = rbase & 511;
                    uchar4 o;
                    o.x = f2e4m3(vv[0]); o.y = f2e4m3(vv[1]);
                    o.z = f2e4m3(vv[2]); o.w = f2e4m3(vv[3]);
                    *reinterpret_cast<uchar4*>(vt8 + ((long)((b << 2) + h) * 192 + d) * 512 + k0) = o;
                }
            } else {
#pragma unroll
                for (int rr = 0; rr < 4; rr++) {
                    int row = rbase + rr;
                    if (row >= M) continue;
                    long idx = coff + (long)row * ldc + col;
                    if (OUT == 0)      ((float*)C)[idx] = vv[rr];
                    else if (OUT == 1) ((u16*)C)[idx] = f2bf(vv[rr]);
                    else               ((unsigned char*)C)[idx] = f2e4m3(vv[rr]);
                }
            }
        }
    }
}

// ---------------- fp8 V transpose with zero-pad (CA only) ----------------
__global__ __launch_bounds__(256) void transpose_pad8(
    const unsigned char* __restrict__ V, long sVb, long sVh, int ldv, int NH,
    unsigned char* __restrict__ VT, long sVT, int rowsIn, int Kp)
{
    __shared__ unsigned char tile[32][33];
    int z = blockIdx.z, zb = z / NH, zh = z % NH;
    const unsigned char* Vp = V + (long)zb * sVb + (long)zh * sVh;
    int k0 = blockIdx.x * 32, d0 = blockIdx.y * 32;
#pragma unroll
    for (int i = 0; i < 4; i++) {
        int k = k0 + threadIdx.y + i * 8;
        int d = d0 + threadIdx.x;
        tile[threadIdx.y + i * 8][threadIdx.x] = (k < rowsIn) ? Vp[(long)k * ldv + d] : (unsigned char)0;
    }
    __syncthreads();
    unsigned char* Op = VT + (long)z * sVT;
#pragma unroll
    for (int i = 0; i < 4; i++) {
        int d = d0 + threadIdx.y + i * 8;
        int k = k0 + threadIdx.x;
        Op[(long)d * Kp + k] = tile[threadIdx.x][threadIdx.y + i * 8];
    }
}

// ---------------- wave-per-row softmax: bf16 scores -> fp8 probs x64 ----------------
template<int CPL, int CAUSAL>
__global__ __launch_bounds__(256) void softmax2(
    const u16* __restrict__ S, unsigned char* __restrict__ P,
    int ld_in, int valid_in, int ld_out, float scale)
{
    int wid = threadIdx.x >> 6, lane = threadIdx.x & 63;
    long r = (long)blockIdx.x * 4 + wid;
    int q = (int)(r & 511);
    int valid = CAUSAL ? (q + 1) : valid_in;
    const u16* srow = S + r * (long)ld_in;
    unsigned char* prow = P + r * (long)ld_out;
    int base = lane * CPL;
    float v[CPL];
    if constexpr (CPL == 8) {
        u16x8 x = *reinterpret_cast<const u16x8*>(srow + base);
#pragma unroll
        for (int j = 0; j < 8; j++) v[j] = bf2f(x[j]);
    } else {
        u16x4 x = *reinterpret_cast<const u16x4*>(srow + base);
#pragma unroll
        for (int j = 0; j < 4; j++) v[j] = bf2f(x[j]);
    }
    float mx = -3e38f;
#pragma unroll
    for (int j = 0; j < CPL; j++) {
        v[j] *= scale;
        if (base + j < valid) mx = fmaxf(mx, v[j]);
    }
#pragma unroll
    for (int o = 32; o; o >>= 1) mx = fmaxf(mx, __shfl_xor(mx, o, 64));
    float e[CPL], s = 0.f;
#pragma unroll
    for (int j = 0; j < CPL; j++) {
        e[j] = (base + j < valid) ? __expf(v[j] - mx) : 0.f;
        s += e[j];
    }
#pragma unroll
    for (int o = 32; o; o >>= 1) s += __shfl_xor(s, o, 64);
    float inv = 64.f / s;                 // probs x64 (PV outscale 1/64)
    if constexpr (CPL == 8) {
        union { unsigned char b[8]; i64 v8; } o;
#pragma unroll
        for (int j = 0; j < 8; j++) o.b[j] = f2e4m3(e[j] * inv);
        *reinterpret_cast<i64*>(prow + base) = o.v8;
    } else {
        uchar4 o4;
        o4.x = f2e4m3(e[0] * inv); o4.y = f2e4m3(e[1] * inv);
        o4.z = f2e4m3(e[2] * inv); o4.w = f2e4m3(e[3] * inv);
        *reinterpret_cast<uchar4*>(prow + base) = o4;
    }
}

// ---------------- fused residual add + LayerNorm (bf16 in/out + fp8 out) ----------------
__global__ __launch_bounds__(256) void ln_kernel(
    const u16* __restrict__ xin, const u16* __restrict__ subb,
    const float* __restrict__ g, const float* __restrict__ bta,
    u16* __restrict__ xout, unsigned char* __restrict__ q8)
{
    int wid = threadIdx.x >> 6, lane = threadIdx.x & 63;
    long r = (long)blockIdx.x * 4 + wid;
    const u16* a = xin + r * 768;
    const u16* s = subb + r * 768;
    int base = lane * 12;
    float v[12];
    float sum = 0.f;
#pragma unroll
    for (int c = 0; c < 3; c++) {
        ushort4 av = *reinterpret_cast<const ushort4*>(a + base + c * 4);
        ushort4 sv = *reinterpret_cast<const ushort4*>(s + base + c * 4);
        v[c*4+0] = bf2f(av.x) + bf2f(sv.x);
        v[c*4+1] = bf2f(av.y) + bf2f(sv.y);
        v[c*4+2] = bf2f(av.z) + bf2f(sv.z);
        v[c*4+3] = bf2f(av.w) + bf2f(sv.w);
        sum += v[c*4+0] + v[c*4+1] + v[c*4+2] + v[c*4+3];
    }
#pragma unroll
    for (int o = 32; o; o >>= 1) sum += __shfl_xor(sum, o, 64);
    float mean = sum * (1.f / 768.f);
    float vs = 0.f;
#pragma unroll
    for (int j = 0; j < 12; j++) { float t = v[j] - mean; vs += t * t; }
#pragma unroll
    for (int o = 32; o; o >>= 1) vs += __shfl_xor(vs, o, 64);
    float rstd = rsqrtf(vs * (1.f / 768.f) + 1e-5f);
    u16* xo = xout + r * 768;
    unsigned char* qo = q8 + r * 768;
#pragma unroll
    for (int c = 0; c < 3; c++) {
        float4 gv = *reinterpret_cast<const float4*>(g + base + c * 4);
        float4 bv = *reinterpret_cast<const float4*>(bta + base + c * 4);
        float y0 = (v[c*4+0] - mean) * rstd * gv.x + bv.x;
        float y1 = (v[c*4+1] - mean) * rstd * gv.y + bv.y;
        float y2 = (v[c*4+2] - mean) * rstd * gv.z + bv.z;
        float y3 = (v[c*4+3] - mean) * rstd * gv.w + bv.w;
        ushort4 o; o.x = f2bf(y0); o.y = f2bf(y1); o.z = f2bf(y2); o.w = f2bf(y3);
        *reinterpret_cast<ushort4*>(xo + base + c * 4) = o;
        uchar4 qb; qb.x = f2e4m3(y0); qb.y = f2e4m3(y1); qb.z = f2e4m3(y2); qb.w = f2e4m3(y3);
        *reinterpret_cast<uchar4*>(qo + base + c * 4) = qb;
    }
}

// ---------------- host helpers ----------------
template<int OUT, int RELU, int BM>
static void g8(hipStream_t st, const unsigned char* A, int lda, const unsigned char* W, int ldw,
               const float* bias, void* C, int ldc, int M, int N, int K) {
    dim3 g((N + 127) / 128, (M + BM - 1) / BM, 1), b(256, 1, 1);
    gemm8<OUT,RELU,BM,0,0><<<g,b,0,st>>>(A,lda,0,0,W,ldw,0,0,bias,1.f/256.f,C,ldc,0,0,nullptr,M,N,K,1);
}
template<int OUT, int CMODE>
static void g8bat(hipStream_t st,
    const unsigned char* A, int lda, long sAb, long sAh,
    const unsigned char* W, int ldw, long sWb, long sWh,
    float outscale, void* C, int ldc, long sCb, long sCh,
    int M, int N, int K, int Z, int NH) {
    dim3 g((N + 127) / 128, (M + 127) / 128, Z), b(256, 1, 1);
    gemm8<OUT,0,128,0,CMODE><<<g,b,0,st>>>(A,lda,sAb,sAh,W,ldw,sWb,sWh,nullptr,outscale,
                                           C,ldc,sCb,sCh,nullptr,M,N,K,NH);
}
static void g8qkv(hipStream_t st, const unsigned char* A, const unsigned char* W,
                  const float* bias, unsigned char* q8k8, unsigned char* vt8) {
    dim3 g(18, 64, 1), b(256, 1, 1);
    gemm8<2,0,128,1,0><<<g,b,0,st>>>(A,768,0,0,W,768,0,0,bias,1.f/256.f,
                                     q8k8,1536,0,0,vt8,8192,2304,768,1);
}

extern "C" void kernel_launch(void* const* d_in, const int* in_sizes, int n_in,
                              void* d_out, int out_size, void* d_ws, size_t ws_size,
                              hipStream_t stream)
{
    const int*   labels = (const int*)  d_in[0];
    const float* vision = (const float*)d_in[1];
    const float* vpw    = (const float*)d_in[2];
    const float* vpb    = (const float*)d_in[3];
    const float* temb   = (const float*)d_in[4];
    const float* pemb   = (const float*)d_in[5];
    const float* saw    = (const float*)d_in[6];
    const float* sab    = (const float*)d_in[7];
    const float* saow   = (const float*)d_in[8];
    const float* saob   = (const float*)d_in[9];
    const float* caw    = (const float*)d_in[10];
    const float* cab    = (const float*)d_in[11];
    const float* caow   = (const float*)d_in[12];
    const float* caob   = (const float*)d_in[13];
    const float* ln1g   = (const float*)d_in[14];
    const float* ln1b   = (const float*)d_in[15];
    const float* ln2g   = (const float*)d_in[16];
    const float* ln2b   = (const float*)d_in[17];
    const float* ln3g   = (const float*)d_in[18];
    const float* ln3b   = (const float*)d_in[19];
    const float* f1w    = (const float*)d_in[20];
    const float* f1b    = (const float*)d_in[21];
    const float* f2w    = (const float*)d_in[22];
    const float* f2b    = (const float*)d_in[23];
    const float* ow     = (const float*)d_in[24];
    const float* ob     = (const float*)d_in[25];
    (void)in_sizes; (void)n_in; (void)out_size;

    // ---- workspace layout ----
    char* p = (char*)d_ws;
    auto alloc = [&](long elems, int esz) -> char* {
        char* r = p; p += ((long)elems * esz + 255) & ~255L; return r;
    };
    unsigned char* w8_sa  = (unsigned char*)alloc(3L*2304*768, 1);  // fp8 weights x256
    unsigned char* w8_ca  = (unsigned char*)alloc(3L*2304*768, 1);
    unsigned char* w8_sao = (unsigned char*)alloc(3L*768*768, 1);
    unsigned char* w8_cao = (unsigned char*)alloc(3L*768*768, 1);
    unsigned char* w8_f1  = (unsigned char*)alloc(3L*1024*768, 1);
    unsigned char* w8_f2  = (unsigned char*)alloc(3L*768*1024, 1);
    unsigned char* w8_ow  = (unsigned char*)alloc(10000L*768, 1);
    unsigned char* w8_vp  = (unsigned char*)alloc(768L*768, 1);
    unsigned char* vis8   = (unsigned char*)alloc(3152L*768, 1);    // fp8 activations (x1)
    unsigned char* mem8   = (unsigned char*)alloc(3152L*768, 1);
    unsigned char* xq     = (unsigned char*)alloc(8192L*768, 1);
    unsigned char* h8     = (unsigned char*)alloc(8192L*1024, 1);
    unsigned char* attn8  = (unsigned char*)alloc(8192L*768, 1);
    unsigned char* q8k8   = (unsigned char*)alloc(8192L*1536, 1);   // SA Q|K fp8
    unsigned char* q8ca   = (unsigned char*)alloc(8192L*768, 1);    // CA Q fp8
    unsigned char* kv8    = (unsigned char*)alloc(3152L*1536, 1);   // CA K|V fp8
    unsigned char* vt8    = (unsigned char*)alloc(64L*192*512, 1);  // V^T fp8 (SA Kp512 / CA Kp256)
    unsigned char* pr8    = (unsigned char*)alloc(64L*512*512, 1);  // probs fp8 x64
    u16* xb   = (u16*)alloc(8192L*768, 2);
    u16* scb  = (u16*)alloc(64L*512*512, 2);                        // bf16 scores
    u16* subb = (u16*)alloc(8192L*768, 2);
    if ((size_t)(p - (char*)d_ws) > ws_size) return;

    // ---- all casts -> fp8 in one launch (weights x256, vision x1) ----
    CastQ cq;
    cq.s[0] = saw;    cq.d[0] = w8_sa;  cq.n4[0] = 3L*2304*768/4;  cq.mul[0] = 256.f;
    cq.s[1] = caw;    cq.d[1] = w8_ca;  cq.n4[1] = 3L*2304*768/4;  cq.mul[1] = 256.f;
    cq.s[2] = saow;   cq.d[2] = w8_sao; cq.n4[2] = 3L*768*768/4;   cq.mul[2] = 256.f;
    cq.s[3] = caow;   cq.d[3] = w8_cao; cq.n4[3] = 3L*768*768/4;   cq.mul[3] = 256.f;
    cq.s[4] = f1w;    cq.d[4] = w8_f1;  cq.n4[4] = 3L*1024*768/4;  cq.mul[4] = 256.f;
    cq.s[5] = f2w;    cq.d[5] = w8_f2;  cq.n4[5] = 3L*768*1024/4;  cq.mul[5] = 256.f;
    cq.s[6] = ow;     cq.d[6] = w8_ow;  cq.n4[6] = 10000L*768/4;   cq.mul[6] = 256.f;
    cq.s[7] = vpw;    cq.d[7] = w8_vp;  cq.n4[7] = 768L*768/4;     cq.mul[7] = 256.f;
    cq.s[8] = vision; cq.d[8] = vis8;   cq.n4[8] = 3152L*768/4;    cq.mul[8] = 1.f;
    castq_kernel<<<dim3(512, 1, 9), dim3(256), 0, stream>>>(cq);

    embed_kernel<<<dim3(2048), dim3(256), 0, stream>>>(labels, temb, pemb, xb, xq,
                                                       (float*)d_out + 81920000L);

    // mem = vision @ vis_proj_w^T + b  -> fp8
    g8<2,0,64>(stream, vis8, 768, w8_vp, 768, vpb, mem8, 768, 3152, 768, 768);

    const float scale = 0.07216878364870323f;  // 1/sqrt(192)
    const float PSCALE_INV = 1.f / 64.f;

    for (int l = 0; l < 3; l++) {
        // ======== self-attention (all fp8, causal-pruned) ========
        g8qkv(stream, xq, w8_sa + (long)l*2304*768, sab + l*2304, q8k8, vt8);
        // scores = Q K^T : causal block-skip (CMODE=1), K=192 (nt=3 guarded), out bf16 scb
        g8bat<1,1>(stream, q8k8, 1536, 512L*1536, 192, q8k8 + 768, 1536, 512L*1536, 192,
                   1.f, scb, 512, 4L*512*512, 512L*512, 512, 512, 192, 64, 4);
        softmax2<8,1><<<dim3(8192), dim3(256), 0, stream>>>(scb, pr8, 512, 512, 512, scale);
        // O = P(x64) @ V^T : causal K-limit (CMODE=2), outscale 1/64, out fp8 attn8
        g8bat<2,2>(stream, pr8, 512, 4L*512*512, 512L*512, vt8, 512, 4L*192*512, 192L*512,
                   PSCALE_INV, attn8, 768, 512L*768, 192, 512, 192, 512, 64, 4);
        g8<1,0,64>(stream, attn8, 768, w8_sao + (long)l*768*768, 768,
                   saob + l*768, subb, 768, 8192, 768, 768);
        ln_kernel<<<dim3(2048), dim3(256), 0, stream>>>(xb, subb, ln1g + l*768, ln1b + l*768,
                                                        xb, xq);

        // ======== cross-attention (all fp8) ========
        g8<2,0,64>(stream, xq, 768, w8_ca + (long)l*2304*768, 768,
                   cab + l*2304, q8ca, 768, 8192, 768, 768);
        g8<2,0,64>(stream, mem8, 768, w8_ca + (long)l*2304*768 + 768L*768, 768,
                   cab + l*2304 + 768, kv8, 1536, 3152, 1536, 768);
        transpose_pad8<<<dim3(8,6,64), dim3(32,8), 0, stream>>>(
            kv8 + 768, 197L*1536, 192L, 1536, 4, vt8, 192L*256, 197, 256);
        g8bat<1,0>(stream, q8ca, 768, 512L*768, 192, kv8, 1536, 197L*1536, 192,
                   1.f, scb, 224, 4L*512*224, 512L*224, 512, 197, 192, 64, 4);
        softmax2<4,0><<<dim3(8192), dim3(256), 0, stream>>>(scb, pr8, 224, 197, 256, scale);
        g8bat<2,0>(stream, pr8, 256, 4L*512*256, 512L*256, vt8, 256, 4L*192*256, 192L*256,
                   PSCALE_INV, attn8, 768, 512L*768, 192, 512, 192, 256, 64, 4);
        g8<1,0,64>(stream, attn8, 768, w8_cao + (long)l*768*768, 768,
                   caob + l*768, subb, 768, 8192, 768, 768);
        ln_kernel<<<dim3(2048), dim3(256), 0, stream>>>(xb, subb, ln2g + l*768, ln2b + l*768,
                                                        xb, xq);

        // ======== feed-forward (fp8) ========
        g8<2,1,128>(stream, xq, 768, w8_f1 + (long)l*1024*768, 768, f1b + l*1024,
                    h8, 1024, 8192, 1024, 768);
        g8<1,0,64>(stream, h8, 1024, w8_f2 + (long)l*768*1024, 1024, f2b + l*768,
                   subb, 768, 8192, 768, 1024);
        ln_kernel<<<dim3(2048), dim3(256), 0, stream>>>(xb, subb, ln3g + l*768, ln3b + l*768,
                                                        xb, xq);
    }

    // vocab head (fp8, BM=128) -> d_out f32 logits
    g8<0,0,128>(stream, xq, 768, w8_ow, 768, ob, (float*)d_out, 10000, 8192, 10000, 768);
}

// Round 15
// 1066.550 us; speedup vs baseline: 1.1109x; 1.0010x over previous
//
#include <hip/hip_runtime.h>
#include <hip/hip_fp8.h>

typedef unsigned short u16;
typedef float f32x4 __attribute__((ext_vector_type(4)));
typedef unsigned short u16x8 __attribute__((ext_vector_type(8)));
typedef unsigned short u16x4 __attribute__((ext_vector_type(4)));
typedef long i64;

typedef __attribute__((address_space(3))) unsigned char lds_u8_t;
typedef __attribute__((address_space(1))) const unsigned char glb_u8_t;

__device__ __forceinline__ u16 f2bf(float f) {
    union { float f; unsigned u; } v; v.f = f;
    unsigned r = v.u + 0x7FFFu + ((v.u >> 16) & 1u);   // RNE
    return (u16)(r >> 16);
}
__device__ __forceinline__ float bf2f(u16 h) {
    union { unsigned u; float f; } v; v.u = ((unsigned)h) << 16; return v.f;
}
__device__ __forceinline__ unsigned char f2e4m3(float f) {
    __hip_fp8_e4m3 h(f);               // OCP e4m3fn, RNE+sat
    return (unsigned char)h.__x;
}

// ---------------- merged f32 -> fp8 cast: 9 segments, per-segment scale ----------------
struct CastQ { const float* s[9]; unsigned char* d[9]; long n4[9]; float mul[9]; };
__global__ __launch_bounds__(256) void castq_kernel(CastQ a) {
    int seg = blockIdx.z;
    const float* s = a.s[seg];
    unsigned char* d = a.d[seg];
    long n4 = a.n4[seg];
    float mul = a.mul[seg];
    long i = (long)blockIdx.x * 256 + threadIdx.x;
    long stride = (long)gridDim.x * 256;
    for (; i < n4; i += stride) {
        float4 f = reinterpret_cast<const float4*>(s)[i];
        uchar4 o;
        o.x = f2e4m3(f.x * mul); o.y = f2e4m3(f.y * mul);
        o.z = f2e4m3(f.z * mul); o.w = f2e4m3(f.w * mul);
        reinterpret_cast<uchar4*>(d)[i] = o;
    }
}

// ---------------- token + positional embedding (wave-per-row), bf16 + fp8 out + labels ----------------
__global__ __launch_bounds__(256) void embed_kernel(
    const int* __restrict__ labels, const float* __restrict__ tok_emb,
    const float* __restrict__ pos_emb, u16* __restrict__ xb,
    unsigned char* __restrict__ xq, float* __restrict__ lab_out)
{
    int wid = threadIdx.x >> 6, lane = threadIdx.x & 63;
    int r = blockIdx.x * 4 + wid;       // 0..8191 = b*512+t
    int b = r >> 9, t = r & 511;
    int tok = labels[b * 513 + t];      // labels[:, :-1]
    if (lane == 0) lab_out[r] = (float)labels[b * 513 + t + 1];
    const float* te = tok_emb + (long)tok * 768;
    const float* pe = pos_emb + (long)t * 768;
    u16* xo = xb + (long)r * 768;
    unsigned char* qo = xq + (long)r * 768;
    int base = lane * 12;
#pragma unroll
    for (int c = 0; c < 3; c++) {
        float4 a = *reinterpret_cast<const float4*>(te + base + c * 4);
        float4 p = *reinterpret_cast<const float4*>(pe + base + c * 4);
        float v0 = a.x + p.x, v1 = a.y + p.y, v2 = a.z + p.z, v3 = a.w + p.w;
        ushort4 o; o.x = f2bf(v0); o.y = f2bf(v1); o.z = f2bf(v2); o.w = f2bf(v3);
        *reinterpret_cast<ushort4*>(xo + base + c * 4) = o;
        uchar4 q; q.x = f2e4m3(v0); q.y = f2e4m3(v1); q.z = f2e4m3(v2); q.w = f2e4m3(v3);
        *reinterpret_cast<uchar4*>(qo + base + c * 4) = q;
    }
}

// ================= BMx128 FP8 MFMA GEMM, BK=64, 2-phase, swizzled LDS, BATCHED =================
// LDS per matrix: halves (k 0..31 / 32..63), 32-B rows, 16-B chunk ^= (row>>2)&1 on BOTH sides.
// OUT: 0=f32, 1=bf16, 2=fp8. QKV: cols<1536 -> fp8 C (ld 1536); cols>=1536 -> fp8 V^T scatter.
// CMODE: 0=none, 1=causal block-skip, 2=causal K-limit (bit-exact).
// Occupancy: BM=128 -> 32 KB LDS, 5 blocks/CU (exactly fills 160 KB); BM=64 -> 24 KB, 6 blocks/CU.
// VGPR=64 supports 8 waves/SIMD, so min-waves declaration is the binding constraint.
template<int OUT, int RELU, int BM, int QKV, int CMODE>
__global__ __launch_bounds__(256, (BM == 128) ? 5 : 6) void gemm8(
    const unsigned char* __restrict__ A, int lda, long sAb, long sAh,
    const unsigned char* __restrict__ W, int ldw, long sWb, long sWh,
    const float* __restrict__ bias, float outscale,
    void* __restrict__ C, int ldc, long sCb, long sCh,
    unsigned char* __restrict__ vt8,
    int M, int N, int K, int NH)
{
    constexpr int NREP = (BM == 128) ? 4 : 2;
    constexpr int AHALF = (BM == 128) ? 4096 : 2048;
    __shared__ __align__(16) unsigned char As0[BM * 64];
    __shared__ __align__(16) unsigned char As1[BM * 64];
    __shared__ __align__(16) unsigned char Bs0[128 * 64];
    __shared__ __align__(16) unsigned char Bs1[128 * 64];

    int z = blockIdx.z, zb = z / NH, zh = z % NH;
    const unsigned char* Ap = A + (long)zb * sAb + (long)zh * sAh;
    const unsigned char* Wp = W + (long)zb * sWb + (long)zh * sWh;
    long coff = (long)zb * sCb + (long)zh * sCh;

    int gx = (int)gridDim.x, gy = (int)gridDim.y;
    int nwg = gx * gy;
    int orig = (int)(blockIdx.y * gridDim.x + blockIdx.x);
    int q = nwg >> 3, r = nwg & 7;
    int xcd = orig & 7, loc = orig >> 3;
    int wg = (xcd < r ? xcd * (q + 1) : r * (q + 1) + (xcd - r) * q) + loc;
    int full = 8 * gy;
    int nsc = (gx + 7) >> 3;
    int sc = wg / full; if (sc > nsc - 1) sc = nsc - 1;
    int rem = wg - sc * full;
    int wdt = gx - sc * 8; if (wdt > 8) wdt = 8;
    int by = rem / wdt, bx = sc * 8 + rem % wdt;

    int m0 = by * BM, n0 = bx * 128;

    // causal block-skip: these score columns are never read by the causal softmax (exact)
    if constexpr (CMODE == 1) { if (n0 > m0 + BM - 1) return; }
    int Keff = K;
    if constexpr (CMODE == 2) { Keff = min(K, m0 + BM); }   // P is exactly 0 beyond q+1

    int tid = threadIdx.x, wid = tid >> 6, lane = tid & 63;
    int wr = (BM == 128) ? (wid >> 1) * 64 : 0;
    int wc = (BM == 128) ? (wid & 1) * 64 : wid * 32;
    int fr = lane & 15, gk = (lane >> 4) * 8;

    // ---- staging geometry (validated swizzle: chunk ^= (row>>2)&1) ----
    int li0 = wid * 64 + lane;
    int rsW = li0 >> 1, csW = li0 & 1;
    int kcW = ((csW ^ (rsW >> 2)) & 1) << 4;
    long woff = (long)min(n0 + rsW, N - 1) * ldw + kcW;
    long aoff;
    if constexpr (BM == 128) {
        aoff = (long)min(m0 + rsW, M - 1) * lda + kcW;
    } else {
        int halfA = li0 >> 7;
        int rsA = (li0 >> 1) & 63, csA = li0 & 1;
        int kcA = ((csA ^ (rsA >> 2)) & 1) << 4;
        aoff = (long)min(m0 + rsA, M - 1) * lda + halfA * 32 + kcA;
    }
    char* a0base = (char*)As0 + wid * 1024;
    char* a1base = (char*)As1 + wid * 1024;
    char* b0base = (char*)Bs0 + wid * 1024;
    char* b1base = (char*)Bs1 + wid * 1024;

    f32x4 acc[4][NREP] = {};

    auto stage = [&](char* ab, char* bb, int kt) {
        int k0 = kt * 64;
        if constexpr (BM == 128) {
            __builtin_amdgcn_global_load_lds((glb_u8_t*)(Ap + aoff + k0), (lds_u8_t*)ab, 16, 0, 0);
            __builtin_amdgcn_global_load_lds((glb_u8_t*)(Ap + aoff + k0 + 32), (lds_u8_t*)(ab + 4096), 16, 0, 0);
        } else {
            __builtin_amdgcn_global_load_lds((glb_u8_t*)(Ap + aoff + k0), (lds_u8_t*)ab, 16, 0, 0);
        }
        __builtin_amdgcn_global_load_lds((glb_u8_t*)(Wp + woff + k0), (lds_u8_t*)bb, 16, 0, 0);
        __builtin_amdgcn_global_load_lds((glb_u8_t*)(Wp + woff + k0 + 32), (lds_u8_t*)(bb + 4096), 16, 0, 0);
    };
    int cg = gk >> 4, go = gk & 15;
    auto compute = [&](const unsigned char* as, const unsigned char* bs) {
        i64 af[4][2], bw[NREP][2];
#pragma unroll
        for (int m = 0; m < 4; m++) {
            int rr2 = wr + m * 16 + fr;
            int off = rr2 * 32 + (((cg ^ (rr2 >> 2)) & 1) << 4) + go;
            af[m][0] = *reinterpret_cast<const i64*>(as + off);
            af[m][1] = *reinterpret_cast<const i64*>(as + AHALF + off);
        }
#pragma unroll
        for (int n = 0; n < NREP; n++) {
            int rr2 = wc + n * 16 + fr;
            int off = rr2 * 32 + (((cg ^ (rr2 >> 2)) & 1) << 4) + go;
            bw[n][0] = *reinterpret_cast<const i64*>(bs + off);
            bw[n][1] = *reinterpret_cast<const i64*>(bs + 4096 + off);
        }
#pragma unroll
        for (int ks = 0; ks < 2; ks++)
#pragma unroll
            for (int m = 0; m < 4; m++)
#pragma unroll
                for (int n = 0; n < NREP; n++)
                    acc[m][n] = __builtin_amdgcn_mfma_f32_16x16x32_fp8_fp8(
                        af[m][ks], bw[n][ks], acc[m][n], 0, 0, 0);
    };

    // guarded 2-phase loop: correct for any nt >= 1 (nt=3 for K=192)
    int nt = Keff >> 6;
    stage(a0base, b0base, 0);
    __syncthreads();
    for (int t = 0; t < nt; t += 2) {
        if (t + 1 < nt) stage(a1base, b1base, t + 1);
        compute(As0, Bs0);
        __syncthreads();
        if (t + 1 < nt) {
            if (t + 2 < nt) stage(a0base, b0base, t + 2);
            compute(As1, Bs1);
            __syncthreads();
        }
    }

    int crow = (lane >> 4) * 4;
#pragma unroll
    for (int m = 0; m < 4; m++) {
#pragma unroll
        for (int n = 0; n < NREP; n++) {
            int col = n0 + wc + n * 16 + fr;
            if (col >= N) continue;
            float bv = bias ? bias[col] : 0.f;
            int rbase = m0 + wr + m * 16 + crow;
            float vv[4];
#pragma unroll
            for (int rr = 0; rr < 4; rr++) {
                float v = acc[m][n][rr] * outscale + bv;
                if (RELU) v = fmaxf(v, 0.f);
                vv[rr] = v;
            }
            if constexpr (QKV) {
                // M=8192, N=2304 exact: no edge checks. cols<1536 -> q8k8; else V^T fp8 scatter.
                if (col < 1536) {
#pragma unroll
                    for (int rr = 0; rr < 4; rr++)
                        ((unsigned char*)C)[coff + (long)(rbase + rr) * ldc + col] = f2e4m3(vv[rr]);
                } else {
                    int tt = col - 1536;
                    int h = tt / 192, d = tt - h * 192;
                    int b = rbase >> 9, k0 = rbase & 511;
                    uchar4 o;
                    o.x = f2e4m3(vv[0]); o.y = f2e4m3(vv[1]);
                    o.z = f2e4m3(vv[2]); o.w = f2e4m3(vv[3]);
                    *reinterpret_cast<uchar4*>(vt8 + ((long)((b << 2) + h) * 192 + d) * 512 + k0) = o;
                }
            } else {
#pragma unroll
                for (int rr = 0; rr < 4; rr++) {
                    int row = rbase + rr;
                    if (row >= M) continue;
                    long idx = coff + (long)row * ldc + col;
                    if (OUT == 0)      ((float*)C)[idx] = vv[rr];
                    else if (OUT == 1) ((u16*)C)[idx] = f2bf(vv[rr]);
                    else               ((unsigned char*)C)[idx] = f2e4m3(vv[rr]);
                }
            }
        }
    }
}

// ---------------- fp8 V transpose with zero-pad (CA only) ----------------
__global__ __launch_bounds__(256) void transpose_pad8(
    const unsigned char* __restrict__ V, long sVb, long sVh, int ldv, int NH,
    unsigned char* __restrict__ VT, long sVT, int rowsIn, int Kp)
{
    __shared__ unsigned char tile[32][33];
    int z = blockIdx.z, zb = z / NH, zh = z % NH;
    const unsigned char* Vp = V + (long)zb * sVb + (long)zh * sVh;
    int k0 = blockIdx.x * 32, d0 = blockIdx.y * 32;
#pragma unroll
    for (int i = 0; i < 4; i++) {
        int k = k0 + threadIdx.y + i * 8;
        int d = d0 + threadIdx.x;
        tile[threadIdx.y + i * 8][threadIdx.x] = (k < rowsIn) ? Vp[(long)k * ldv + d] : (unsigned char)0;
    }
    __syncthreads();
    unsigned char* Op = VT + (long)z * sVT;
#pragma unroll
    for (int i = 0; i < 4; i++) {
        int d = d0 + threadIdx.y + i * 8;
        int k = k0 + threadIdx.x;
        Op[(long)d * Kp + k] = tile[threadIdx.x][threadIdx.y + i * 8];
    }
}

// ---------------- wave-per-row softmax: bf16 scores -> fp8 probs x64 ----------------
template<int CPL, int CAUSAL>
__global__ __launch_bounds__(256) void softmax2(
    const u16* __restrict__ S, unsigned char* __restrict__ P,
    int ld_in, int valid_in, int ld_out, float scale)
{
    int wid = threadIdx.x >> 6, lane = threadIdx.x & 63;
    long r = (long)blockIdx.x * 4 + wid;
    int q = (int)(r & 511);
    int valid = CAUSAL ? (q + 1) : valid_in;
    const u16* srow = S + r * (long)ld_in;
    unsigned char* prow = P + r * (long)ld_out;
    int base = lane * CPL;
    float v[CPL];
    if constexpr (CPL == 8) {
        u16x8 x = *reinterpret_cast<const u16x8*>(srow + base);
#pragma unroll
        for (int j = 0; j < 8; j++) v[j] = bf2f(x[j]);
    } else {
        u16x4 x = *reinterpret_cast<const u16x4*>(srow + base);
#pragma unroll
        for (int j = 0; j < 4; j++) v[j] = bf2f(x[j]);
    }
    float mx = -3e38f;
#pragma unroll
    for (int j = 0; j < CPL; j++) {
        v[j] *= scale;
        if (base + j < valid) mx = fmaxf(mx, v[j]);
    }
#pragma unroll
    for (int o = 32; o; o >>= 1) mx = fmaxf(mx, __shfl_xor(mx, o, 64));
    float e[CPL], s = 0.f;
#pragma unroll
    for (int j = 0; j < CPL; j++) {
        e[j] = (base + j < valid) ? __expf(v[j] - mx) : 0.f;
        s += e[j];
    }
#pragma unroll
    for (int o = 32; o; o >>= 1) s += __shfl_xor(s, o, 64);
    float inv = 64.f / s;                 // probs x64 (PV outscale 1/64)
    if constexpr (CPL == 8) {
        union { unsigned char b[8]; i64 v8; } o;
#pragma unroll
        for (int j = 0; j < 8; j++) o.b[j] = f2e4m3(e[j] * inv);
        *reinterpret_cast<i64*>(prow + base) = o.v8;
    } else {
        uchar4 o4;
        o4.x = f2e4m3(e[0] * inv); o4.y = f2e4m3(e[1] * inv);
        o4.z = f2e4m3(e[2] * inv); o4.w = f2e4m3(e[3] * inv);
        *reinterpret_cast<uchar4*>(prow + base) = o4;
    }
}

// ---------------- fused residual add + LayerNorm (bf16 in/out + fp8 out) ----------------
__global__ __launch_bounds__(256) void ln_kernel(
    const u16* __restrict__ xin, const u16* __restrict__ subb,
    const float* __restrict__ g, const float* __restrict__ bta,
    u16* __restrict__ xout, unsigned char* __restrict__ q8)
{
    int wid = threadIdx.x >> 6, lane = threadIdx.x & 63;
    long r = (long)blockIdx.x * 4 + wid;
    const u16* a = xin + r * 768;
    const u16* s = subb + r * 768;
    int base = lane * 12;
    float v[12];
    float sum = 0.f;
#pragma unroll
    for (int c = 0; c < 3; c++) {
        ushort4 av = *reinterpret_cast<const ushort4*>(a + base + c * 4);
        ushort4 sv = *reinterpret_cast<const ushort4*>(s + base + c * 4);
        v[c*4+0] = bf2f(av.x) + bf2f(sv.x);
        v[c*4+1] = bf2f(av.y) + bf2f(sv.y);
        v[c*4+2] = bf2f(av.z) + bf2f(sv.z);
        v[c*4+3] = bf2f(av.w) + bf2f(sv.w);
        sum += v[c*4+0] + v[c*4+1] + v[c*4+2] + v[c*4+3];
    }
#pragma unroll
    for (int o = 32; o; o >>= 1) sum += __shfl_xor(sum, o, 64);
    float mean = sum * (1.f / 768.f);
    float vs = 0.f;
#pragma unroll
    for (int j = 0; j < 12; j++) { float t = v[j] - mean; vs += t * t; }
#pragma unroll
    for (int o = 32; o; o >>= 1) vs += __shfl_xor(vs, o, 64);
    float rstd = rsqrtf(vs * (1.f / 768.f) + 1e-5f);
    u16* xo = xout + r * 768;
    unsigned char* qo = q8 + r * 768;
#pragma unroll
    for (int c = 0; c < 3; c++) {
        float4 gv = *reinterpret_cast<const float4*>(g + base + c * 4);
        float4 bv = *reinterpret_cast<const float4*>(bta + base + c * 4);
        float y0 = (v[c*4+0] - mean) * rstd * gv.x + bv.x;
        float y1 = (v[c*4+1] - mean) * rstd * gv.y + bv.y;
        float y2 = (v[c*4+2] - mean) * rstd * gv.z + bv.z;
        float y3 = (v[c*4+3] - mean) * rstd * gv.w + bv.w;
        ushort4 o; o.x = f2bf(y0); o.y = f2bf(y1); o.z = f2bf(y2); o.w = f2bf(y3);
        *reinterpret_cast<ushort4*>(xo + base + c * 4) = o;
        uchar4 qb; qb.x = f2e4m3(y0); qb.y = f2e4m3(y1); qb.z = f2e4m3(y2); qb.w = f2e4m3(y3);
        *reinterpret_cast<uchar4*>(qo + base + c * 4) = qb;
    }
}

// ---------------- host helpers ----------------
template<int OUT, int RELU, int BM>
static void g8(hipStream_t st, const unsigned char* A, int lda, const unsigned char* W, int ldw,
               const float* bias, void* C, int ldc, int M, int N, int K) {
    dim3 g((N + 127) / 128, (M + BM - 1) / BM, 1), b(256, 1, 1);
    gemm8<OUT,RELU,BM,0,0><<<g,b,0,st>>>(A,lda,0,0,W,ldw,0,0,bias,1.f/256.f,C,ldc,0,0,nullptr,M,N,K,1);
}
template<int OUT, int CMODE>
static void g8bat(hipStream_t st,
    const unsigned char* A, int lda, long sAb, long sAh,
    const unsigned char* W, int ldw, long sWb, long sWh,
    float outscale, void* C, int ldc, long sCb, long sCh,
    int M, int N, int K, int Z, int NH) {
    dim3 g((N + 127) / 128, (M + 127) / 128, Z), b(256, 1, 1);
    gemm8<OUT,0,128,0,CMODE><<<g,b,0,st>>>(A,lda,sAb,sAh,W,ldw,sWb,sWh,nullptr,outscale,
                                           C,ldc,sCb,sCh,nullptr,M,N,K,NH);
}
static void g8qkv(hipStream_t st, const unsigned char* A, const unsigned char* W,
                  const float* bias, unsigned char* q8k8, unsigned char* vt8) {
    dim3 g(18, 64, 1), b(256, 1, 1);
    gemm8<2,0,128,1,0><<<g,b,0,st>>>(A,768,0,0,W,768,0,0,bias,1.f/256.f,
                                     q8k8,1536,0,0,vt8,8192,2304,768,1);
}

extern "C" void kernel_launch(void* const* d_in, const int* in_sizes, int n_in,
                              void* d_out, int out_size, void* d_ws, size_t ws_size,
                              hipStream_t stream)
{
    const int*   labels = (const int*)  d_in[0];
    const float* vision = (const float*)d_in[1];
    const float* vpw    = (const float*)d_in[2];
    const float* vpb    = (const float*)d_in[3];
    const float* temb   = (const float*)d_in[4];
    const float* pemb   = (const float*)d_in[5];
    const float* saw    = (const float*)d_in[6];
    const float* sab    = (const float*)d_in[7];
    const float* saow   = (const float*)d_in[8];
    const float* saob   = (const float*)d_in[9];
    const float* caw    = (const float*)d_in[10];
    const float* cab    = (const float*)d_in[11];
    const float* caow   = (const float*)d_in[12];
    const float* caob   = (const float*)d_in[13];
    const float* ln1g   = (const float*)d_in[14];
    const float* ln1b   = (const float*)d_in[15];
    const float* ln2g   = (const float*)d_in[16];
    const float* ln2b   = (const float*)d_in[17];
    const float* ln3g   = (const float*)d_in[18];
    const float* ln3b   = (const float*)d_in[19];
    const float* f1w    = (const float*)d_in[20];
    const float* f1b    = (const float*)d_in[21];
    const float* f2w    = (const float*)d_in[22];
    const float* f2b    = (const float*)d_in[23];
    const float* ow     = (const float*)d_in[24];
    const float* ob     = (const float*)d_in[25];
    (void)in_sizes; (void)n_in; (void)out_size;

    // ---- workspace layout ----
    char* p = (char*)d_ws;
    auto alloc = [&](long elems, int esz) -> char* {
        char* r = p; p += ((long)elems * esz + 255) & ~255L; return r;
    };
    unsigned char* w8_sa  = (unsigned char*)alloc(3L*2304*768, 1);  // fp8 weights x256
    unsigned char* w8_ca  = (unsigned char*)alloc(3L*2304*768, 1);
    unsigned char* w8_sao = (unsigned char*)alloc(3L*768*768, 1);
    unsigned char* w8_cao = (unsigned char*)alloc(3L*768*768, 1);
    unsigned char* w8_f1  = (unsigned char*)alloc(3L*1024*768, 1);
    unsigned char* w8_f2  = (unsigned char*)alloc(3L*768*1024, 1);
    unsigned char* w8_ow  = (unsigned char*)alloc(10000L*768, 1);
    unsigned char* w8_vp  = (unsigned char*)alloc(768L*768, 1);
    unsigned char* vis8   = (unsigned char*)alloc(3152L*768, 1);    // fp8 activations (x1)
    unsigned char* mem8   = (unsigned char*)alloc(3152L*768, 1);
    unsigned char* xq     = (unsigned char*)alloc(8192L*768, 1);
    unsigned char* h8     = (unsigned char*)alloc(8192L*1024, 1);
    unsigned char* attn8  = (unsigned char*)alloc(8192L*768, 1);
    unsigned char* q8k8   = (unsigned char*)alloc(8192L*1536, 1);   // SA Q|K fp8
    unsigned char* q8ca   = (unsigned char*)alloc(8192L*768, 1);    // CA Q fp8
    unsigned char* kv8    = (unsigned char*)alloc(3152L*1536, 1);   // CA K|V fp8
    unsigned char* vt8    = (unsigned char*)alloc(64L*192*512, 1);  // V^T fp8 (SA Kp512 / CA Kp256)
    unsigned char* pr8    = (unsigned char*)alloc(64L*512*512, 1);  // probs fp8 x64
    u16* xb   = (u16*)alloc(8192L*768, 2);
    u16* scb  = (u16*)alloc(64L*512*512, 2);                        // bf16 scores
    u16* subb = (u16*)alloc(8192L*768, 2);
    if ((size_t)(p - (char*)d_ws) > ws_size) return;

    // ---- all casts -> fp8 in one launch (weights x256, vision x1) ----
    CastQ cq;
    cq.s[0] = saw;    cq.d[0] = w8_sa;  cq.n4[0] = 3L*2304*768/4;  cq.mul[0] = 256.f;
    cq.s[1] = caw;    cq.d[1] = w8_ca;  cq.n4[1] = 3L*2304*768/4;  cq.mul[1] = 256.f;
    cq.s[2] = saow;   cq.d[2] = w8_sao; cq.n4[2] = 3L*768*768/4;   cq.mul[2] = 256.f;
    cq.s[3] = caow;   cq.d[3] = w8_cao; cq.n4[3] = 3L*768*768/4;   cq.mul[3] = 256.f;
    cq.s[4] = f1w;    cq.d[4] = w8_f1;  cq.n4[4] = 3L*1024*768/4;  cq.mul[4] = 256.f;
    cq.s[5] = f2w;    cq.d[5] = w8_f2;  cq.n4[5] = 3L*768*1024/4;  cq.mul[5] = 256.f;
    cq.s[6] = ow;     cq.d[6] = w8_ow;  cq.n4[6] = 10000L*768/4;   cq.mul[6] = 256.f;
    cq.s[7] = vpw;    cq.d[7] = w8_vp;  cq.n4[7] = 768L*768/4;     cq.mul[7] = 256.f;
    cq.s[8] = vision; cq.d[8] = vis8;   cq.n4[8] = 3152L*768/4;    cq.mul[8] = 1.f;
    castq_kernel<<<dim3(512, 1, 9), dim3(256), 0, stream>>>(cq);

    embed_kernel<<<dim3(2048), dim3(256), 0, stream>>>(labels, temb, pemb, xb, xq,
                                                       (float*)d_out + 81920000L);

    // mem = vision @ vis_proj_w^T + b  -> fp8
    g8<2,0,64>(stream, vis8, 768, w8_vp, 768, vpb, mem8, 768, 3152, 768, 768);

    const float scale = 0.07216878364870323f;  // 1/sqrt(192)
    const float PSCALE_INV = 1.f / 64.f;

    for (int l = 0; l < 3; l++) {
        // ======== self-attention (all fp8, causal-pruned) ========
        g8qkv(stream, xq, w8_sa + (long)l*2304*768, sab + l*2304, q8k8, vt8);
        // scores = Q K^T : causal block-skip (CMODE=1), K=192 (nt=3 guarded), out bf16 scb
        g8bat<1,1>(stream, q8k8, 1536, 512L*1536, 192, q8k8 + 768, 1536, 512L*1536, 192,
                   1.f, scb, 512, 4L*512*512, 512L*512, 512, 512, 192, 64, 4);
        softmax2<8,1><<<dim3(8192), dim3(256), 0, stream>>>(scb, pr8, 512, 512, 512, scale);
        // O = P(x64) @ V^T : causal K-limit (CMODE=2), outscale 1/64, out fp8 attn8
        g8bat<2,2>(stream, pr8, 512, 4L*512*512, 512L*512, vt8, 512, 4L*192*512, 192L*512,
                   PSCALE_INV, attn8, 768, 512L*768, 192, 512, 192, 512, 64, 4);
        g8<1,0,64>(stream, attn8, 768, w8_sao + (long)l*768*768, 768,
                   saob + l*768, subb, 768, 8192, 768, 768);
        ln_kernel<<<dim3(2048), dim3(256), 0, stream>>>(xb, subb, ln1g + l*768, ln1b + l*768,
                                                        xb, xq);

        // ======== cross-attention (all fp8) ========
        g8<2,0,64>(stream, xq, 768, w8_ca + (long)l*2304*768, 768,
                   cab + l*2304, q8ca, 768, 8192, 768, 768);
        g8<2,0,64>(stream, mem8, 768, w8_ca + (long)l*2304*768 + 768L*768, 768,
                   cab + l*2304 + 768, kv8, 1536, 3152, 1536, 768);
        transpose_pad8<<<dim3(8,6,64), dim3(32,8), 0, stream>>>(
            kv8 + 768, 197L*1536, 192L, 1536, 4, vt8, 192L*256, 197, 256);
        g8bat<1,0>(stream, q8ca, 768, 512L*768, 192, kv8, 1536, 197L*1536, 192,
                   1.f, scb, 224, 4L*512*224, 512L*224, 512, 197, 192, 64, 4);
        softmax2<4,0><<<dim3(8192), dim3(256), 0, stream>>>(scb, pr8, 224, 197, 256, scale);
        g8bat<2,0>(stream, pr8, 256, 4L*512*256, 512L*256, vt8, 256, 4L*192*256, 192L*256,
                   PSCALE_INV, attn8, 768, 512L*768, 192, 512, 192, 256, 64, 4);
        g8<1,0,64>(stream, attn8, 768, w8_cao + (long)l*768*768, 768,
                   caob + l*768, subb, 768, 8192, 768, 768);
        ln_kernel<<<dim3(2048), dim3(256), 0, stream>>>(xb, subb, ln2g + l*768, ln2b + l*768,
                                                        xb, xq);

        // ======== feed-forward (fp8) ========
        g8<2,1,128>(stream, xq, 768, w8_f1 + (long)l*1024*768, 768, f1b + l*1024,
                    h8, 1024, 8192, 1024, 768);
        g8<1,0,64>(stream, h8, 1024, w8_f2 + (long)l*768*1024, 1024, f2b + l*768,
                   subb, 768, 8192, 768, 1024);
        ln_kernel<<<dim3(2048), dim3(256), 0, stream>>>(xb, subb, ln3g + l*768, ln3b + l*768,
                                                        xb, xq);
    }

    // vocab head (fp8, BM=128) -> d_out f32 logits
    g8<0,0,128>(stream, xq, 768, w8_ow, 768, ob, (float*)d_out, 10000, 8192, 10000, 768);
}